// Round 3
// baseline (790.906 us; speedup 1.0000x reference)
//
#include <hip/hip_runtime.h>
#include <math.h>

#define B_ 16
#define S_ 512
#define D_ 768
#define H_ 12
#define DH_ 64
#define BH_ (B_*H_)     // 192
#define MTOT (B_*S_)    // 8192
#define NTOT (3*D_)     // 2304

typedef unsigned short ushort_t;
typedef __attribute__((ext_vector_type(8))) short bf16x8;
typedef __attribute__((ext_vector_type(4))) float f32x4;

__device__ __forceinline__ unsigned short f2bf(float x){
    unsigned u = __float_as_uint(x);
    unsigned r = (u + 0x7FFFu + ((u >> 16) & 1u)) >> 16;
    return (unsigned short)r;
}
__device__ __forceinline__ float bf2f(unsigned short b){
    return __uint_as_float(((unsigned)b) << 16);
}

__device__ __forceinline__ void cp16(const void* g, void* l){
    __builtin_amdgcn_global_load_lds(
        (const __attribute__((address_space(1))) unsigned int*)g,
        (__attribute__((address_space(3))) unsigned int*)l, 16, 0, 0);
}

// ---------------------------------------------------------------------------
// f32 -> single bf16 (round-to-nearest), 4 elems/thread
// ---------------------------------------------------------------------------
__global__ __launch_bounds__(256)
void convert_x(const float* __restrict__ src, ushort_t* __restrict__ dst, int n4)
{
    int i = blockIdx.x * 256 + threadIdx.x;
    if (i >= n4) return;
    float4 x = ((const float4*)src)[i];
    union { ushort_t u[4]; uint2 v; } p;
    p.u[0] = f2bf(x.x); p.u[1] = f2bf(x.y);
    p.u[2] = f2bf(x.z); p.u[3] = f2bf(x.w);
    ((uint2*)dst)[i] = p.v;
}

// weights: split hi/lo, all three matrices in one launch
__global__ __launch_bounds__(256)
void convert_w(const float* __restrict__ Wq, const float* __restrict__ Wk,
               const float* __restrict__ Wv, ushort_t* __restrict__ hi,
               ushort_t* __restrict__ lo)
{
    const float* src = (blockIdx.z==0) ? Wq : (blockIdx.z==1) ? Wk : Wv;
    const int n4 = D_*D_/4;
    int i = blockIdx.x * 256 + threadIdx.x;
    if (i >= n4) return;
    size_t off4 = (size_t)blockIdx.z * n4;
    float4 x = ((const float4*)src)[i];
    union { ushort_t u[4]; uint2 v; } ph, pl;
    float xs[4] = {x.x, x.y, x.z, x.w};
    #pragma unroll
    for (int c = 0; c < 4; c++){
        unsigned short h = f2bf(xs[c]);
        ph.u[c] = h;
        pl.u[c] = f2bf(xs[c] - bf2f(h));
    }
    ((uint2*)hi)[off4 + i] = ph.v;
    ((uint2*)lo)[off4 + i] = pl.v;
}

// ---------------------------------------------------------------------------
// MFMA GEMM: C[m,n] = sum_k Xbf[m,k] * W[n,k] + bias; X single bf16, W hi/lo
// (2 MFMAs per tile-pair). mat 0 -> Q hi/lo, 1 -> K hi/lo,
// 2 -> V TRANSPOSED hi/lo (V^T[bh][d][s], bf16 split) for MFMA PV.
// ---------------------------------------------------------------------------
#define BM 128
#define BN 128
#define BK 32

__global__ __launch_bounds__(256)
void gemm_split(const ushort_t* __restrict__ A,
                const ushort_t* __restrict__ Bhi, const ushort_t* __restrict__ Blo,
                const float* __restrict__ bq, const float* __restrict__ bk,
                const float* __restrict__ bv,
                ushort_t* __restrict__ qhi, ushort_t* __restrict__ qlo,
                ushort_t* __restrict__ khi, ushort_t* __restrict__ klo,
                ushort_t* __restrict__ vthi, ushort_t* __restrict__ vtlo)
{
    __shared__ ushort_t Ah[BM*BK], Bh[BN*BK], Bl[BN*BK];  // 24 KB

    const int tid  = threadIdx.x;
    const int lane = tid & 63, wave = tid >> 6;
    const int m0 = blockIdx.y * BM, n0 = blockIdx.x * BN;
    const int wm = (wave >> 1) * 64, wn = (wave & 1) * 64;

    f32x4 acc[4][4];
    #pragma unroll
    for (int i=0;i<4;i++)
        #pragma unroll
        for (int j=0;j<4;j++) acc[i][j] = (f32x4){0.f,0.f,0.f,0.f};

    const int r0 = tid >> 2, c0 = (tid & 3) * 8;
    const size_t ga0 = (size_t)(m0 + r0)      * D_ + c0;
    const size_t ga1 = (size_t)(m0 + 64 + r0) * D_ + c0;
    const size_t gb0 = (size_t)(n0 + r0)      * D_ + c0;
    const size_t gb1 = (size_t)(n0 + 64 + r0) * D_ + c0;
    const int l0 = wave * 512;
    const int l1 = 2048 + wave * 512;

    const int fr = lane & 15, kc = (lane >> 4) * 8;

    for (int k0 = 0; k0 < D_; k0 += BK) {
        cp16(A   + ga0 + k0, Ah + l0);
        cp16(A   + ga1 + k0, Ah + l1);
        cp16(Bhi + gb0 + k0, Bh + l0);
        cp16(Bhi + gb1 + k0, Bh + l1);
        cp16(Blo + gb0 + k0, Bl + l0);
        cp16(Blo + gb1 + k0, Bl + l1);
        __syncthreads();

        bf16x8 fa[4], fbh[4], fbl[4];
        #pragma unroll
        for (int i = 0; i < 4; i++){
            fa[i]  = *(const bf16x8*)&Ah[(wm + i*16 + fr)*BK + kc];
            fbh[i] = *(const bf16x8*)&Bh[(wn + i*16 + fr)*BK + kc];
            fbl[i] = *(const bf16x8*)&Bl[(wn + i*16 + fr)*BK + kc];
        }
        #pragma unroll
        for (int i = 0; i < 4; i++)
            #pragma unroll
            for (int j = 0; j < 4; j++){
                acc[i][j] = __builtin_amdgcn_mfma_f32_16x16x32_bf16(fa[i], fbh[j], acc[i][j], 0,0,0);
                acc[i][j] = __builtin_amdgcn_mfma_f32_16x16x32_bf16(fa[i], fbl[j], acc[i][j], 0,0,0);
            }
        __syncthreads();
    }

    const int mat = n0 / D_;   // block-uniform
    const float* bias = (mat==0) ? bq : (mat==1) ? bk : bv;
    const int col = lane & 15, rbase = (lane >> 4) * 4;
    #pragma unroll
    for (int j = 0; j < 4; j++){
        int nn = n0 + wn + j*16 + col - mat*D_;
        int h = nn >> 6, d = nn & 63;
        float bsv = bias[nn];
        if (mat == 2){
            // V^T hi/lo: thread owns 4 consecutive s (r=0..3) at fixed d
            #pragma unroll
            for (int i = 0; i < 4; i++){
                int m = m0 + wm + i*16 + rbase;          // s0; bb/s const over r
                int bb = m >> 9, s = m & 511;
                size_t idx = (((size_t)bb*H_ + h)*DH_ + d)*S_ + s;
                ushort4 vh4, vl4;
                ushort_t* hp = (ushort_t*)&vh4;
                ushort_t* lp = (ushort_t*)&vl4;
                #pragma unroll
                for (int r = 0; r < 4; r++){
                    float val = acc[i][j][r] + bsv;
                    ushort_t hv = f2bf(val);
                    hp[r] = hv;
                    lp[r] = f2bf(val - bf2f(hv));
                }
                *(ushort4*)&vthi[idx] = vh4;
                *(ushort4*)&vtlo[idx] = vl4;
            }
        } else {
            #pragma unroll
            for (int i = 0; i < 4; i++){
                #pragma unroll
                for (int r = 0; r < 4; r++){
                    int m = m0 + wm + i*16 + rbase + r;
                    int bb = m >> 9, s = m & 511;
                    size_t idx = (((size_t)bb*H_ + h)*S_ + s)*DH_ + d;
                    float val = acc[i][j][r] + bsv;
                    ushort_t hv = f2bf(val);
                    ushort_t lv = f2bf(val - bf2f(hv));
                    if (mat == 0){ qhi[idx] = hv; qlo[idx] = lv; }
                    else         { khi[idx] = hv; klo[idx] = lv; }
                }
            }
        }
    }
}

// ---------------------------------------------------------------------------
// MFMA sparsemax attention, occupancy-optimized: LDS = 20,480 B -> 8 blk/CU.
// Score exchange done in 2 halves of one 16KB-class buffer; lane fr owns keys
// {fr*16+[0,16)} U {256+fr*16+[0,16)}. PV-MFMA runs in 2 passes over a single
// 16KB P-fragment buffer: pass A = Ph*Vh + Ph*Vl, pass B = Pl*Vh (accumulators
// were independent before, so math identical). P packed once to bf16-pair
// registers (pkh/pkl), written twice.
// ---------------------------------------------------------------------------
#define SROW 320   // f32 per row: 16 owners x 20 (16 keys + 4 pad)

__global__ __launch_bounds__(256, 8)
void attn_mfma(const ushort_t* __restrict__ Qhi, const ushort_t* __restrict__ Qlo,
               const ushort_t* __restrict__ Khi, const ushort_t* __restrict__ Klo,
               const ushort_t* __restrict__ Vthi, const ushort_t* __restrict__ Vtlo,
               const float* __restrict__ mask, float* __restrict__ out)
{
    __shared__ float sc[16*SROW];   // 20,480 B; reused as P-fragment buffer

    const int lane = threadIdx.x & 63;
    const int wave = threadIdx.x >> 6;         // 0..3
    const int fr = lane & 15, quad = lane >> 4;

    // XCD-bijective swizzle: 6144 blocks, 768 per XCD => 24 whole heads/XCD
    const int orig = blockIdx.x;
    const int swz  = (orig & 7) * (BH_*32/8) + (orig >> 3);
    const int bh = swz >> 5;
    const int q0 = (swz & 31) * 16;
    const int b = bh / H_, h = bh % H_;
    const size_t hb = (size_t)bh * S_ * DH_;

    // ---- Phase 1: QK^T scores (Q hi/lo x K hi/lo, 6 MFMAs per tile) -------
    bf16x8 qh[2], ql[2];
    {
        const ushort_t* qp  = Qhi + hb + (size_t)(q0 + fr)*DH_ + quad*8;
        const ushort_t* qp2 = Qlo + hb + (size_t)(q0 + fr)*DH_ + quad*8;
        qh[0] = *(const bf16x8*)qp;   qh[1] = *(const bf16x8*)(qp + 32);
        ql[0] = *(const bf16x8*)qp2;  ql[1] = *(const bf16x8*)(qp2 + 32);
    }

    f32x4 acc2[2][4];
    #pragma unroll
    for (int h2=0;h2<2;h2++)
        #pragma unroll
        for (int jj=0;jj<4;jj++) acc2[h2][jj] = (f32x4){0.f,0.f,0.f,0.f};

    __builtin_amdgcn_s_setprio(1);
    #pragma unroll
    for (int h2=0;h2<2;h2++){
        #pragma unroll
        for (int jj=0;jj<4;jj++){
            int kt = h2*256 + wave*64 + jj*16;
            const ushort_t* kp  = Khi + hb + (size_t)(kt + fr)*DH_ + quad*8;
            const ushort_t* kp2 = Klo + hb + (size_t)(kt + fr)*DH_ + quad*8;
            bf16x8 kh0 = *(const bf16x8*)kp;
            bf16x8 kh1 = *(const bf16x8*)(kp + 32);
            bf16x8 kl0 = *(const bf16x8*)kp2;
            bf16x8 kl1 = *(const bf16x8*)(kp2 + 32);
            f32x4 a = acc2[h2][jj];
            a = __builtin_amdgcn_mfma_f32_16x16x32_bf16(qh[0], kh0, a, 0,0,0);
            a = __builtin_amdgcn_mfma_f32_16x16x32_bf16(qh[1], kh1, a, 0,0,0);
            a = __builtin_amdgcn_mfma_f32_16x16x32_bf16(ql[0], kh0, a, 0,0,0);
            a = __builtin_amdgcn_mfma_f32_16x16x32_bf16(ql[1], kh1, a, 0,0,0);
            a = __builtin_amdgcn_mfma_f32_16x16x32_bf16(qh[0], kl0, a, 0,0,0);
            a = __builtin_amdgcn_mfma_f32_16x16x32_bf16(qh[1], kl1, a, 0,0,0);
            acc2[h2][jj] = a;
        }
    }
    __builtin_amdgcn_s_setprio(0);

    // ---- Half-exchange: scatter half0, read z[0..16), scatter half1, read
    const float* mrow = mask + b * S_;
    const int row = wave*4 + quad;
    float z[32];

    #pragma unroll
    for (int jj=0;jj<4;jj++){
        int k = wave*64 + jj*16 + fr;
        float mv = mrow[k];
        int o = wave*4 + jj;
        #pragma unroll
        for (int r=0;r<4;r++)
            sc[(quad*4+r)*SROW + o*20 + fr] = acc2[0][jj][r]*0.125f + mv;
    }
    __syncthreads();
    {
        const float* zp = &sc[row*SROW + fr*20];
        #pragma unroll
        for (int jj=0;jj<4;jj++){
            float4 t = *(const float4*)(zp + jj*4);
            z[jj*4+0]=t.x; z[jj*4+1]=t.y; z[jj*4+2]=t.z; z[jj*4+3]=t.w;
        }
    }
    __syncthreads();
    #pragma unroll
    for (int jj=0;jj<4;jj++){
        int k = 256 + wave*64 + jj*16 + fr;
        float mv = mrow[k];
        int o = wave*4 + jj;
        #pragma unroll
        for (int r=0;r<4;r++)
            sc[(quad*4+r)*SROW + o*20 + fr] = acc2[1][jj][r]*0.125f + mv;
    }
    __syncthreads();
    {
        const float* zp = &sc[row*SROW + fr*20];
        #pragma unroll
        for (int jj=0;jj<4;jj++){
            float4 t = *(const float4*)(zp + jj*4);
            z[16+jj*4+0]=t.x; z[16+jj*4+1]=t.y; z[16+jj*4+2]=t.z; z[16+jj*4+3]=t.w;
        }
    }
    __syncthreads();   // all reads done; sc may be overwritten by P frags

    // ---- Row max: depth-5 tree + 4-step intra-quad butterfly --------------
    float tau;
    {
        float red[16];
        #pragma unroll
        for (int i=0;i<16;i++) red[i] = fmaxf(z[i], z[i+16]);
        #pragma unroll
        for (int i=0;i<8;i++)  red[i] = fmaxf(red[i], red[i+8]);
        #pragma unroll
        for (int i=0;i<4;i++)  red[i] = fmaxf(red[i], red[i+4]);
        float mm = fmaxf(fmaxf(red[0],red[1]), fmaxf(red[2],red[3]));
        #pragma unroll
        for (int off=1; off<16; off<<=1) mm = fmaxf(mm, __shfl_xor(mm, off, 64));
        tau = mm - 1.0f;
    }

    // ---- Michelot fixed-point: 4-way partial sums, butterfly --------------
    for (int it=0; it<16; it++){
        float s0=0.f,s1=0.f,s2=0.f,s3=0.f;
        float k0=0.f,k1=0.f,k2=0.f,k3=0.f;
        #pragma unroll
        for (int i=0;i<32;i+=4){
            float z0=z[i], z1=z[i+1], z2=z[i+2], z3=z[i+3];
            if (z0 > tau){ s0 += z0; k0 += 1.f; }
            if (z1 > tau){ s1 += z1; k1 += 1.f; }
            if (z2 > tau){ s2 += z2; k2 += 1.f; }
            if (z3 > tau){ s3 += z3; k3 += 1.f; }
        }
        float ss = (s0+s1)+(s2+s3), kk = (k0+k1)+(k2+k3);
        #pragma unroll
        for (int off=1; off<16; off<<=1){
            ss += __shfl_xor(ss, off, 64);
            kk += __shfl_xor(kk, off, 64);
        }
        float tn = (ss - 1.0f) / kk;
        bool changed = (tn != tau);
        tau = tn;
        if (!__any(changed)) break;
    }

    // ---- Pack p = max(z - tau, 0) to bf16 hi/lo pair registers ------------
    // pkh[j]/pkl[j] hold values (2j, 2j+1) as packed 2 x bf16 (low = 2j).
    unsigned pkh[16], pkl[16];
    #pragma unroll
    for (int j=0;j<16;j++){
        float p0 = z[2*j]   - tau; p0 = p0 > 0.f ? p0 : 0.f;
        float p1 = z[2*j+1] - tau; p1 = p1 > 0.f ? p1 : 0.f;
        unsigned b0 = __float_as_uint(p0), b1 = __float_as_uint(p1);
        pkh[j] = (b0 >> 16) | (b1 & 0xFFFF0000u);           // trunc hi
        float d0 = p0 - __uint_as_float(b0 & 0xFFFF0000u);
        float d1 = p1 - __uint_as_float(b1 & 0xFFFF0000u);
        pkl[j] = (unsigned)f2bf(d0) | (((unsigned)f2bf(d1)) << 16);  // RNE lo
    }

    // ---- P_hi frags -> LDS. Unit u(c,qq,row) = c*64 + qq*16 + (row^(c&7));
    // unit holds keys [32c+8qq, +8). This thread: c = h2*8 + (fr>>1),
    // qq = (fr&1)*2 + e, data = pkh[h2*8+e*4 .. +4].
    ushort_t* Pf = (ushort_t*)sc;
    #pragma unroll
    for (int h2=0;h2<2;h2++)
        #pragma unroll
        for (int e=0;e<2;e++){
            int c = h2*8 + (fr>>1);
            int u = c*64 + ((fr&1)*2+e)*16 + (row ^ (c&7));
            int s0i = h2*8 + e*4;
            uint4 w4 = make_uint4(pkh[s0i], pkh[s0i+1], pkh[s0i+2], pkh[s0i+3]);
            *(uint4*)&Pf[u*8] = w4;
        }
    __syncthreads();

    // ---- PV pass A: Ph*Vh + Ph*Vl. Wave w owns d-slice [16w, 16w+16). -----
    const int d0w = wave * 16;
    const ushort_t* vph = Vthi + ((size_t)bh*DH_ + d0w + fr)*S_ + quad*8;
    const ushort_t* vpl = Vtlo + ((size_t)bh*DH_ + d0w + fr)*S_ + quad*8;

    f32x4 aH = (f32x4){0.f,0.f,0.f,0.f};
    f32x4 aL = (f32x4){0.f,0.f,0.f,0.f};
    __builtin_amdgcn_s_setprio(1);
    #pragma unroll
    for (int c=0; c<16; c++){
        int u = c*64 + quad*16 + (fr ^ (c & 7));
        bf16x8 ah  = *(const bf16x8*)&Pf[u*8];
        bf16x8 vh8 = *(const bf16x8*)(vph + c*32);
        bf16x8 vl8 = *(const bf16x8*)(vpl + c*32);
        aH = __builtin_amdgcn_mfma_f32_16x16x32_bf16(ah, vh8, aH, 0,0,0);
        aL = __builtin_amdgcn_mfma_f32_16x16x32_bf16(ah, vl8, aL, 0,0,0);
    }
    __builtin_amdgcn_s_setprio(0);
    __syncthreads();

    // ---- P_lo frags -> LDS (same layout), then PV pass B: Pl*Vh ----------
    #pragma unroll
    for (int h2=0;h2<2;h2++)
        #pragma unroll
        for (int e=0;e<2;e++){
            int c = h2*8 + (fr>>1);
            int u = c*64 + ((fr&1)*2+e)*16 + (row ^ (c&7));
            int s0i = h2*8 + e*4;
            uint4 w4 = make_uint4(pkl[s0i], pkl[s0i+1], pkl[s0i+2], pkl[s0i+3]);
            *(uint4*)&Pf[u*8] = w4;
        }
    __syncthreads();

    f32x4 aC = (f32x4){0.f,0.f,0.f,0.f};
    __builtin_amdgcn_s_setprio(1);
    #pragma unroll
    for (int c=0; c<16; c++){
        int u = c*64 + quad*16 + (fr ^ (c & 7));
        bf16x8 al  = *(const bf16x8*)&Pf[u*8];
        bf16x8 vh8 = *(const bf16x8*)(vph + c*32);
        aC = __builtin_amdgcn_mfma_f32_16x16x32_bf16(al, vh8, aC, 0,0,0);
    }
    __builtin_amdgcn_s_setprio(0);

    f32x4 cs = (aH + aL) + aC;

    // C/D layout: col = lane&15 = d-offset, row = quad*4 + r = q-row
    size_t ob = ((size_t)(b*S_ + q0 + quad*4))*D_ + h*DH_ + d0w + fr;
    #pragma unroll
    for (int r=0; r<4; r++) out[ob + (size_t)r*D_] = cs[r];
}

// ---------------------------------------------------------------------------
extern "C" void kernel_launch(void* const* d_in, const int* in_sizes, int n_in,
                              void* d_out, int out_size, void* d_ws, size_t ws_size,
                              hipStream_t stream) {
    const float* hs   = (const float*)d_in[0];
    const float* mask = (const float*)d_in[1];
    const float* Wq   = (const float*)d_in[2];
    const float* bq   = (const float*)d_in[3];
    const float* Wk   = (const float*)d_in[4];
    const float* bk   = (const float*)d_in[5];
    const float* Wv   = (const float*)d_in[6];
    const float* bv   = (const float*)d_in[7];
    float* out = (float*)d_out;

    const size_t per = (size_t)BH_ * S_ * DH_;   // 6291456
    char* w = (char*)d_ws;
    ushort_t* vthi = (ushort_t*)w; w += per*2;
    ushort_t* vtlo = (ushort_t*)w; w += per*2;
    ushort_t* qhi  = (ushort_t*)w; w += per*2;
    ushort_t* qlo  = (ushort_t*)w; w += per*2;
    ushort_t* khi  = (ushort_t*)w; w += per*2;
    ushort_t* klo  = (ushort_t*)w; w += per*2;
    ushort_t* Xbf  = (ushort_t*)w; w += per*2;
    ushort_t* Whi  = (ushort_t*)w; w += (size_t)NTOT*D_*2;
    ushort_t* Wlo  = (ushort_t*)w;

    convert_x<<<(int)(per/4/256), 256, 0, stream>>>(hs, Xbf, (int)(per/4));
    convert_w<<<dim3(D_*D_/4/256, 1, 3), 256, 0, stream>>>(Wq, Wk, Wv, Whi, Wlo);

    dim3 ggrid(NTOT/BN, MTOT/BM);   // (18, 64)
    gemm_split<<<ggrid, 256, 0, stream>>>(Xbf, Whi, Wlo, bq, bk, bv,
                                          qhi, qlo, khi, klo, vthi, vtlo);

    attn_mfma<<<BH_*32, 256, 0, stream>>>(qhi, qlo, khi, klo, vthi, vtlo, mask, out);
}

// Round 4
// 667.162 us; speedup vs baseline: 1.1855x; 1.1855x over previous
//
#include <hip/hip_runtime.h>
#include <math.h>

#define B_ 16
#define S_ 512
#define D_ 768
#define H_ 12
#define DH_ 64
#define BH_ (B_*H_)     // 192
#define MTOT (B_*S_)    // 8192
#define NTOT (3*D_)     // 2304

typedef unsigned short ushort_t;
typedef __attribute__((ext_vector_type(8))) short bf16x8;
typedef __attribute__((ext_vector_type(4))) float f32x4;

__device__ __forceinline__ unsigned short f2bf(float x){
    unsigned u = __float_as_uint(x);
    unsigned r = (u + 0x7FFFu + ((u >> 16) & 1u)) >> 16;
    return (unsigned short)r;
}
__device__ __forceinline__ float bf2f(unsigned short b){
    return __uint_as_float(((unsigned)b) << 16);
}

__device__ __forceinline__ void cp16(const void* g, void* l){
    __builtin_amdgcn_global_load_lds(
        (const __attribute__((address_space(1))) unsigned int*)g,
        (__attribute__((address_space(3))) unsigned int*)l, 16, 0, 0);
}

// ---------------------------------------------------------------------------
// f32 -> single bf16 (round-to-nearest), 4 elems/thread
// ---------------------------------------------------------------------------
__global__ __launch_bounds__(256)
void convert_x(const float* __restrict__ src, ushort_t* __restrict__ dst, int n4)
{
    int i = blockIdx.x * 256 + threadIdx.x;
    if (i >= n4) return;
    float4 x = ((const float4*)src)[i];
    union { ushort_t u[4]; uint2 v; } p;
    p.u[0] = f2bf(x.x); p.u[1] = f2bf(x.y);
    p.u[2] = f2bf(x.z); p.u[3] = f2bf(x.w);
    ((uint2*)dst)[i] = p.v;
}

// weights: split hi/lo, all three matrices in one launch
__global__ __launch_bounds__(256)
void convert_w(const float* __restrict__ Wq, const float* __restrict__ Wk,
               const float* __restrict__ Wv, ushort_t* __restrict__ hi,
               ushort_t* __restrict__ lo)
{
    const float* src = (blockIdx.z==0) ? Wq : (blockIdx.z==1) ? Wk : Wv;
    const int n4 = D_*D_/4;
    int i = blockIdx.x * 256 + threadIdx.x;
    if (i >= n4) return;
    size_t off4 = (size_t)blockIdx.z * n4;
    float4 x = ((const float4*)src)[i];
    union { ushort_t u[4]; uint2 v; } ph, pl;
    float xs[4] = {x.x, x.y, x.z, x.w};
    #pragma unroll
    for (int c = 0; c < 4; c++){
        unsigned short h = f2bf(xs[c]);
        ph.u[c] = h;
        pl.u[c] = f2bf(xs[c] - bf2f(h));
    }
    ((uint2*)hi)[off4 + i] = ph.v;
    ((uint2*)lo)[off4 + i] = pl.v;
}

// ---------------------------------------------------------------------------
// MFMA GEMM: C[m,n] = sum_k Xbf[m,k] * W[n,k] + bias; X single bf16, W hi/lo
// (2 MFMAs per tile-pair). mat 0 -> Q hi/lo, 1 -> K hi/lo,
// 2 -> V TRANSPOSED hi/lo (V^T[bh][d][s], bf16 split) for MFMA PV.
// ---------------------------------------------------------------------------
#define BM 128
#define BN 128
#define BK 32

__global__ __launch_bounds__(256)
void gemm_split(const ushort_t* __restrict__ A,
                const ushort_t* __restrict__ Bhi, const ushort_t* __restrict__ Blo,
                const float* __restrict__ bq, const float* __restrict__ bk,
                const float* __restrict__ bv,
                ushort_t* __restrict__ qhi, ushort_t* __restrict__ qlo,
                ushort_t* __restrict__ khi, ushort_t* __restrict__ klo,
                ushort_t* __restrict__ vthi, ushort_t* __restrict__ vtlo)
{
    __shared__ ushort_t Ah[BM*BK], Bh[BN*BK], Bl[BN*BK];  // 24 KB

    const int tid  = threadIdx.x;
    const int lane = tid & 63, wave = tid >> 6;
    const int m0 = blockIdx.y * BM, n0 = blockIdx.x * BN;
    const int wm = (wave >> 1) * 64, wn = (wave & 1) * 64;

    f32x4 acc[4][4];
    #pragma unroll
    for (int i=0;i<4;i++)
        #pragma unroll
        for (int j=0;j<4;j++) acc[i][j] = (f32x4){0.f,0.f,0.f,0.f};

    const int r0 = tid >> 2, c0 = (tid & 3) * 8;
    const size_t ga0 = (size_t)(m0 + r0)      * D_ + c0;
    const size_t ga1 = (size_t)(m0 + 64 + r0) * D_ + c0;
    const size_t gb0 = (size_t)(n0 + r0)      * D_ + c0;
    const size_t gb1 = (size_t)(n0 + 64 + r0) * D_ + c0;
    const int l0 = wave * 512;
    const int l1 = 2048 + wave * 512;

    const int fr = lane & 15, kc = (lane >> 4) * 8;

    for (int k0 = 0; k0 < D_; k0 += BK) {
        cp16(A   + ga0 + k0, Ah + l0);
        cp16(A   + ga1 + k0, Ah + l1);
        cp16(Bhi + gb0 + k0, Bh + l0);
        cp16(Bhi + gb1 + k0, Bh + l1);
        cp16(Blo + gb0 + k0, Bl + l0);
        cp16(Blo + gb1 + k0, Bl + l1);
        __syncthreads();

        bf16x8 fa[4], fbh[4], fbl[4];
        #pragma unroll
        for (int i = 0; i < 4; i++){
            fa[i]  = *(const bf16x8*)&Ah[(wm + i*16 + fr)*BK + kc];
            fbh[i] = *(const bf16x8*)&Bh[(wn + i*16 + fr)*BK + kc];
            fbl[i] = *(const bf16x8*)&Bl[(wn + i*16 + fr)*BK + kc];
        }
        #pragma unroll
        for (int i = 0; i < 4; i++)
            #pragma unroll
            for (int j = 0; j < 4; j++){
                acc[i][j] = __builtin_amdgcn_mfma_f32_16x16x32_bf16(fa[i], fbh[j], acc[i][j], 0,0,0);
                acc[i][j] = __builtin_amdgcn_mfma_f32_16x16x32_bf16(fa[i], fbl[j], acc[i][j], 0,0,0);
            }
        __syncthreads();
    }

    const int mat = n0 / D_;   // block-uniform
    const float* bias = (mat==0) ? bq : (mat==1) ? bk : bv;
    const int col = lane & 15, rbase = (lane >> 4) * 4;
    #pragma unroll
    for (int j = 0; j < 4; j++){
        int nn = n0 + wn + j*16 + col - mat*D_;
        int h = nn >> 6, d = nn & 63;
        float bsv = bias[nn];
        if (mat == 2){
            // V^T hi/lo: thread owns 4 consecutive s (r=0..3) at fixed d
            #pragma unroll
            for (int i = 0; i < 4; i++){
                int m = m0 + wm + i*16 + rbase;          // s0; bb/s const over r
                int bb = m >> 9, s = m & 511;
                size_t idx = (((size_t)bb*H_ + h)*DH_ + d)*S_ + s;
                ushort4 vh4, vl4;
                ushort_t* hp = (ushort_t*)&vh4;
                ushort_t* lp = (ushort_t*)&vl4;
                #pragma unroll
                for (int r = 0; r < 4; r++){
                    float val = acc[i][j][r] + bsv;
                    ushort_t hv = f2bf(val);
                    hp[r] = hv;
                    lp[r] = f2bf(val - bf2f(hv));
                }
                *(ushort4*)&vthi[idx] = vh4;
                *(ushort4*)&vtlo[idx] = vl4;
            }
        } else {
            #pragma unroll
            for (int i = 0; i < 4; i++){
                #pragma unroll
                for (int r = 0; r < 4; r++){
                    int m = m0 + wm + i*16 + rbase + r;
                    int bb = m >> 9, s = m & 511;
                    size_t idx = (((size_t)bb*H_ + h)*S_ + s)*DH_ + d;
                    float val = acc[i][j][r] + bsv;
                    ushort_t hv = f2bf(val);
                    ushort_t lv = f2bf(val - bf2f(hv));
                    if (mat == 0){ qhi[idx] = hv; qlo[idx] = lv; }
                    else         { khi[idx] = hv; klo[idx] = lv; }
                }
            }
        }
    }
}

// ---------------------------------------------------------------------------
// MFMA sparsemax attention, occupancy-optimized: LDS = 20,480 B.
// __launch_bounds__(256,6): ~85-VGPR budget -> no spills (r3 lesson: (256,8)
// forced VGPR=32 and spilled 1.7 GB to scratch). Score exchange in 2 halves;
// PV-MFMA in 2 passes over one 16KB P-fragment buffer; P fragments are
// RECOMPUTED from z/tau at each write (no pkh/pkl register arrays).
// ---------------------------------------------------------------------------
#define SROW 320   // f32 per row: 16 owners x 20 (16 keys + 4 pad)

__global__ __launch_bounds__(256, 6)
void attn_mfma(const ushort_t* __restrict__ Qhi, const ushort_t* __restrict__ Qlo,
               const ushort_t* __restrict__ Khi, const ushort_t* __restrict__ Klo,
               const ushort_t* __restrict__ Vthi, const ushort_t* __restrict__ Vtlo,
               const float* __restrict__ mask, float* __restrict__ out)
{
    __shared__ float sc[16*SROW];   // 20,480 B; reused as P-fragment buffer

    const int lane = threadIdx.x & 63;
    const int wave = threadIdx.x >> 6;         // 0..3
    const int fr = lane & 15, quad = lane >> 4;

    // XCD-bijective swizzle: 6144 blocks, 768 per XCD => 24 whole heads/XCD
    const int orig = blockIdx.x;
    const int swz  = (orig & 7) * (BH_*32/8) + (orig >> 3);
    const int bh = swz >> 5;
    const int q0 = (swz & 31) * 16;
    const int b = bh / H_, h = bh % H_;
    const size_t hb = (size_t)bh * S_ * DH_;

    // ---- Phase 1: QK^T scores (Q hi/lo x K hi/lo, 6 MFMAs per tile) -------
    bf16x8 qh[2], ql[2];
    {
        const ushort_t* qp  = Qhi + hb + (size_t)(q0 + fr)*DH_ + quad*8;
        const ushort_t* qp2 = Qlo + hb + (size_t)(q0 + fr)*DH_ + quad*8;
        qh[0] = *(const bf16x8*)qp;   qh[1] = *(const bf16x8*)(qp + 32);
        ql[0] = *(const bf16x8*)qp2;  ql[1] = *(const bf16x8*)(qp2 + 32);
    }

    f32x4 acc2[2][4];
    #pragma unroll
    for (int h2=0;h2<2;h2++)
        #pragma unroll
        for (int jj=0;jj<4;jj++) acc2[h2][jj] = (f32x4){0.f,0.f,0.f,0.f};

    __builtin_amdgcn_s_setprio(1);
    #pragma unroll
    for (int h2=0;h2<2;h2++){
        #pragma unroll
        for (int jj=0;jj<4;jj++){
            int kt = h2*256 + wave*64 + jj*16;
            const ushort_t* kp  = Khi + hb + (size_t)(kt + fr)*DH_ + quad*8;
            const ushort_t* kp2 = Klo + hb + (size_t)(kt + fr)*DH_ + quad*8;
            bf16x8 kh0 = *(const bf16x8*)kp;
            bf16x8 kh1 = *(const bf16x8*)(kp + 32);
            bf16x8 kl0 = *(const bf16x8*)kp2;
            bf16x8 kl1 = *(const bf16x8*)(kp2 + 32);
            f32x4 a = acc2[h2][jj];
            a = __builtin_amdgcn_mfma_f32_16x16x32_bf16(qh[0], kh0, a, 0,0,0);
            a = __builtin_amdgcn_mfma_f32_16x16x32_bf16(qh[1], kh1, a, 0,0,0);
            a = __builtin_amdgcn_mfma_f32_16x16x32_bf16(ql[0], kh0, a, 0,0,0);
            a = __builtin_amdgcn_mfma_f32_16x16x32_bf16(ql[1], kh1, a, 0,0,0);
            a = __builtin_amdgcn_mfma_f32_16x16x32_bf16(qh[0], kl0, a, 0,0,0);
            a = __builtin_amdgcn_mfma_f32_16x16x32_bf16(qh[1], kl1, a, 0,0,0);
            acc2[h2][jj] = a;
        }
    }
    __builtin_amdgcn_s_setprio(0);

    // ---- Half-exchange: scatter half0, read z[0..16), scatter half1, read
    const float* mrow = mask + b * S_;
    const int row = wave*4 + quad;
    float z[32];

    #pragma unroll
    for (int jj=0;jj<4;jj++){
        int k = wave*64 + jj*16 + fr;
        float mv = mrow[k];
        int o = wave*4 + jj;
        #pragma unroll
        for (int r=0;r<4;r++)
            sc[(quad*4+r)*SROW + o*20 + fr] = acc2[0][jj][r]*0.125f + mv;
    }
    __syncthreads();
    {
        const float* zp = &sc[row*SROW + fr*20];
        #pragma unroll
        for (int jj=0;jj<4;jj++){
            float4 t = *(const float4*)(zp + jj*4);
            z[jj*4+0]=t.x; z[jj*4+1]=t.y; z[jj*4+2]=t.z; z[jj*4+3]=t.w;
        }
    }
    __syncthreads();
    #pragma unroll
    for (int jj=0;jj<4;jj++){
        int k = 256 + wave*64 + jj*16 + fr;
        float mv = mrow[k];
        int o = wave*4 + jj;
        #pragma unroll
        for (int r=0;r<4;r++)
            sc[(quad*4+r)*SROW + o*20 + fr] = acc2[1][jj][r]*0.125f + mv;
    }
    __syncthreads();
    {
        const float* zp = &sc[row*SROW + fr*20];
        #pragma unroll
        for (int jj=0;jj<4;jj++){
            float4 t = *(const float4*)(zp + jj*4);
            z[16+jj*4+0]=t.x; z[16+jj*4+1]=t.y; z[16+jj*4+2]=t.z; z[16+jj*4+3]=t.w;
        }
    }
    __syncthreads();   // all reads done; sc may be overwritten by P frags

    // ---- Row max: depth-5 tree + 4-step intra-quad butterfly --------------
    float tau;
    {
        float red[16];
        #pragma unroll
        for (int i=0;i<16;i++) red[i] = fmaxf(z[i], z[i+16]);
        #pragma unroll
        for (int i=0;i<8;i++)  red[i] = fmaxf(red[i], red[i+8]);
        #pragma unroll
        for (int i=0;i<4;i++)  red[i] = fmaxf(red[i], red[i+4]);
        float mm = fmaxf(fmaxf(red[0],red[1]), fmaxf(red[2],red[3]));
        #pragma unroll
        for (int off=1; off<16; off<<=1) mm = fmaxf(mm, __shfl_xor(mm, off, 64));
        tau = mm - 1.0f;
    }

    // ---- Michelot fixed-point: 4-way partial sums, butterfly --------------
    for (int it=0; it<16; it++){
        float s0=0.f,s1=0.f,s2=0.f,s3=0.f;
        float k0=0.f,k1=0.f,k2=0.f,k3=0.f;
        #pragma unroll
        for (int i=0;i<32;i+=4){
            float z0=z[i], z1=z[i+1], z2=z[i+2], z3=z[i+3];
            if (z0 > tau){ s0 += z0; k0 += 1.f; }
            if (z1 > tau){ s1 += z1; k1 += 1.f; }
            if (z2 > tau){ s2 += z2; k2 += 1.f; }
            if (z3 > tau){ s3 += z3; k3 += 1.f; }
        }
        float ss = (s0+s1)+(s2+s3), kk = (k0+k1)+(k2+k3);
        #pragma unroll
        for (int off=1; off<16; off<<=1){
            ss += __shfl_xor(ss, off, 64);
            kk += __shfl_xor(kk, off, 64);
        }
        float tn = (ss - 1.0f) / kk;
        bool changed = (tn != tau);
        tau = tn;
        if (!__any(changed)) break;
    }

    // ---- P_hi frags -> LDS, recomputed from z/tau (no register staging). --
    // Unit u(c,qq,row) = c*64 + qq*16 + (row^(c&7)); unit holds keys
    // [32c+8qq, +8). This thread: c = h2*8 + (fr>>1), qq = (fr&1)*2+e,
    // data = keys 256*h2 + fr*16 + 8e + [0,8) = z[16*h2 + 8e + 0..7].
    ushort_t* Pf = (ushort_t*)sc;
    #pragma unroll
    for (int h2=0;h2<2;h2++)
        #pragma unroll
        for (int e=0;e<2;e++){
            int c = h2*8 + (fr>>1);
            int u = c*64 + ((fr&1)*2+e)*16 + (row ^ (c&7));
            int zb = h2*16 + e*8;
            unsigned wv[4];
            #pragma unroll
            for (int j=0;j<4;j++){
                float p0 = z[zb+2*j]   - tau; p0 = p0 > 0.f ? p0 : 0.f;
                float p1 = z[zb+2*j+1] - tau; p1 = p1 > 0.f ? p1 : 0.f;
                wv[j] = (__float_as_uint(p0) >> 16)
                      | (__float_as_uint(p1) & 0xFFFF0000u);     // trunc hi
            }
            *(uint4*)&Pf[u*8] = make_uint4(wv[0],wv[1],wv[2],wv[3]);
        }
    __syncthreads();

    // ---- PV pass A: Ph*Vh + Ph*Vl. Wave w owns d-slice [16w, 16w+16). -----
    const int d0w = wave * 16;
    const ushort_t* vph = Vthi + ((size_t)bh*DH_ + d0w + fr)*S_ + quad*8;
    const ushort_t* vpl = Vtlo + ((size_t)bh*DH_ + d0w + fr)*S_ + quad*8;

    f32x4 aH = (f32x4){0.f,0.f,0.f,0.f};
    f32x4 aL = (f32x4){0.f,0.f,0.f,0.f};
    __builtin_amdgcn_s_setprio(1);
    #pragma unroll
    for (int c=0; c<16; c++){
        int u = c*64 + quad*16 + (fr ^ (c & 7));
        bf16x8 ah  = *(const bf16x8*)&Pf[u*8];
        bf16x8 vh8 = *(const bf16x8*)(vph + c*32);
        bf16x8 vl8 = *(const bf16x8*)(vpl + c*32);
        aH = __builtin_amdgcn_mfma_f32_16x16x32_bf16(ah, vh8, aH, 0,0,0);
        aL = __builtin_amdgcn_mfma_f32_16x16x32_bf16(ah, vl8, aL, 0,0,0);
    }
    __builtin_amdgcn_s_setprio(0);
    __syncthreads();

    // ---- P_lo frags -> LDS (same layout, recomputed), PV pass B: Pl*Vh ----
    #pragma unroll
    for (int h2=0;h2<2;h2++)
        #pragma unroll
        for (int e=0;e<2;e++){
            int c = h2*8 + (fr>>1);
            int u = c*64 + ((fr&1)*2+e)*16 + (row ^ (c&7));
            int zb = h2*16 + e*8;
            unsigned wv[4];
            #pragma unroll
            for (int j=0;j<4;j++){
                float p0 = z[zb+2*j]   - tau; p0 = p0 > 0.f ? p0 : 0.f;
                float p1 = z[zb+2*j+1] - tau; p1 = p1 > 0.f ? p1 : 0.f;
                unsigned b0 = __float_as_uint(p0), b1 = __float_as_uint(p1);
                float d0 = p0 - __uint_as_float(b0 & 0xFFFF0000u);
                float d1 = p1 - __uint_as_float(b1 & 0xFFFF0000u);
                wv[j] = (unsigned)f2bf(d0) | (((unsigned)f2bf(d1)) << 16);
            }
            *(uint4*)&Pf[u*8] = make_uint4(wv[0],wv[1],wv[2],wv[3]);
        }
    __syncthreads();

    f32x4 aC = (f32x4){0.f,0.f,0.f,0.f};
    __builtin_amdgcn_s_setprio(1);
    #pragma unroll
    for (int c=0; c<16; c++){
        int u = c*64 + quad*16 + (fr ^ (c & 7));
        bf16x8 al  = *(const bf16x8*)&Pf[u*8];
        bf16x8 vh8 = *(const bf16x8*)(vph + c*32);
        aC = __builtin_amdgcn_mfma_f32_16x16x32_bf16(al, vh8, aC, 0,0,0);
    }
    __builtin_amdgcn_s_setprio(0);

    f32x4 cs = (aH + aL) + aC;

    // C/D layout: col = lane&15 = d-offset, row = quad*4 + r = q-row
    size_t ob = ((size_t)(b*S_ + q0 + quad*4))*D_ + h*DH_ + d0w + fr;
    #pragma unroll
    for (int r=0; r<4; r++) out[ob + (size_t)r*D_] = cs[r];
}

// ---------------------------------------------------------------------------
extern "C" void kernel_launch(void* const* d_in, const int* in_sizes, int n_in,
                              void* d_out, int out_size, void* d_ws, size_t ws_size,
                              hipStream_t stream) {
    const float* hs   = (const float*)d_in[0];
    const float* mask = (const float*)d_in[1];
    const float* Wq   = (const float*)d_in[2];
    const float* bq   = (const float*)d_in[3];
    const float* Wk   = (const float*)d_in[4];
    const float* bk   = (const float*)d_in[5];
    const float* Wv   = (const float*)d_in[6];
    const float* bv   = (const float*)d_in[7];
    float* out = (float*)d_out;

    const size_t per = (size_t)BH_ * S_ * DH_;   // 6291456
    char* w = (char*)d_ws;
    ushort_t* vthi = (ushort_t*)w; w += per*2;
    ushort_t* vtlo = (ushort_t*)w; w += per*2;
    ushort_t* qhi  = (ushort_t*)w; w += per*2;
    ushort_t* qlo  = (ushort_t*)w; w += per*2;
    ushort_t* khi  = (ushort_t*)w; w += per*2;
    ushort_t* klo  = (ushort_t*)w; w += per*2;
    ushort_t* Xbf  = (ushort_t*)w; w += per*2;
    ushort_t* Whi  = (ushort_t*)w; w += (size_t)NTOT*D_*2;
    ushort_t* Wlo  = (ushort_t*)w;

    convert_x<<<(int)(per/4/256), 256, 0, stream>>>(hs, Xbf, (int)(per/4));
    convert_w<<<dim3(D_*D_/4/256, 1, 3), 256, 0, stream>>>(Wq, Wk, Wv, Whi, Wlo);

    dim3 ggrid(NTOT/BN, MTOT/BM);   // (18, 64)
    gemm_split<<<ggrid, 256, 0, stream>>>(Xbf, Whi, Wlo, bq, bk, bv,
                                          qhi, qlo, khi, klo, vthi, vtlo);

    attn_mfma<<<BH_*32, 256, 0, stream>>>(qhi, qlo, khi, klo, vthi, vtlo, mask, out);
}

// Round 5
// 315.403 us; speedup vs baseline: 2.5076x; 2.1153x over previous
//
#include <hip/hip_runtime.h>
#include <math.h>

#define B_ 16
#define S_ 512
#define D_ 768
#define H_ 12
#define DH_ 64
#define BH_ (B_*H_)     // 192
#define MTOT (B_*S_)    // 8192
#define NTOT (3*D_)     // 2304

typedef unsigned short ushort_t;
typedef __attribute__((ext_vector_type(8))) short bf16x8;
typedef __attribute__((ext_vector_type(4))) float f32x4;

__device__ __forceinline__ unsigned short f2bf(float x){
    unsigned u = __float_as_uint(x);
    unsigned r = (u + 0x7FFFu + ((u >> 16) & 1u)) >> 16;
    return (unsigned short)r;
}
__device__ __forceinline__ float bf2f(unsigned short b){
    return __uint_as_float(((unsigned)b) << 16);
}

__device__ __forceinline__ void cp16(const void* g, void* l){
    __builtin_amdgcn_global_load_lds(
        (const __attribute__((address_space(1))) unsigned int*)g,
        (__attribute__((address_space(3))) unsigned int*)l, 16, 0, 0);
}

// ---------------------------------------------------------------------------
// f32 -> single bf16 (round-to-nearest), 4 elems/thread
// ---------------------------------------------------------------------------
__global__ __launch_bounds__(256)
void convert_x(const float* __restrict__ src, ushort_t* __restrict__ dst, int n4)
{
    int i = blockIdx.x * 256 + threadIdx.x;
    if (i >= n4) return;
    float4 x = ((const float4*)src)[i];
    union { ushort_t u[4]; uint2 v; } p;
    p.u[0] = f2bf(x.x); p.u[1] = f2bf(x.y);
    p.u[2] = f2bf(x.z); p.u[3] = f2bf(x.w);
    ((uint2*)dst)[i] = p.v;
}

// weights: split hi/lo, all three matrices in one launch
__global__ __launch_bounds__(256)
void convert_w(const float* __restrict__ Wq, const float* __restrict__ Wk,
               const float* __restrict__ Wv, ushort_t* __restrict__ hi,
               ushort_t* __restrict__ lo)
{
    const float* src = (blockIdx.z==0) ? Wq : (blockIdx.z==1) ? Wk : Wv;
    const int n4 = D_*D_/4;
    int i = blockIdx.x * 256 + threadIdx.x;
    if (i >= n4) return;
    size_t off4 = (size_t)blockIdx.z * n4;
    float4 x = ((const float4*)src)[i];
    union { ushort_t u[4]; uint2 v; } ph, pl;
    float xs[4] = {x.x, x.y, x.z, x.w};
    #pragma unroll
    for (int c = 0; c < 4; c++){
        unsigned short h = f2bf(xs[c]);
        ph.u[c] = h;
        pl.u[c] = f2bf(xs[c] - bf2f(h));
    }
    ((uint2*)hi)[off4 + i] = ph.v;
    ((uint2*)lo)[off4 + i] = pl.v;
}

// ---------------------------------------------------------------------------
// MFMA GEMM: C[m,n] = sum_k Xbf[m,k] * W[n,k] + bias; X single bf16, W hi/lo
// (2 MFMAs per tile-pair). mat 0 -> Q hi/lo, 1 -> K hi/lo, 2 -> V f32
// [bh][s][d] (for the sparse ballot-walk PV).
// ---------------------------------------------------------------------------
#define BM 128
#define BN 128
#define BK 32

__global__ __launch_bounds__(256)
void gemm_split(const ushort_t* __restrict__ A,
                const ushort_t* __restrict__ Bhi, const ushort_t* __restrict__ Blo,
                const float* __restrict__ bq, const float* __restrict__ bk,
                const float* __restrict__ bv,
                ushort_t* __restrict__ qhi, ushort_t* __restrict__ qlo,
                ushort_t* __restrict__ khi, ushort_t* __restrict__ klo,
                float* __restrict__ outv)
{
    __shared__ ushort_t Ah[BM*BK], Bh[BN*BK], Bl[BN*BK];  // 24 KB

    const int tid  = threadIdx.x;
    const int lane = tid & 63, wave = tid >> 6;
    const int m0 = blockIdx.y * BM, n0 = blockIdx.x * BN;
    const int wm = (wave >> 1) * 64, wn = (wave & 1) * 64;

    f32x4 acc[4][4];
    #pragma unroll
    for (int i=0;i<4;i++)
        #pragma unroll
        for (int j=0;j<4;j++) acc[i][j] = (f32x4){0.f,0.f,0.f,0.f};

    const int r0 = tid >> 2, c0 = (tid & 3) * 8;
    const size_t ga0 = (size_t)(m0 + r0)      * D_ + c0;
    const size_t ga1 = (size_t)(m0 + 64 + r0) * D_ + c0;
    const size_t gb0 = (size_t)(n0 + r0)      * D_ + c0;
    const size_t gb1 = (size_t)(n0 + 64 + r0) * D_ + c0;
    const int l0 = wave * 512;
    const int l1 = 2048 + wave * 512;

    const int fr = lane & 15, kc = (lane >> 4) * 8;

    for (int k0 = 0; k0 < D_; k0 += BK) {
        cp16(A   + ga0 + k0, Ah + l0);
        cp16(A   + ga1 + k0, Ah + l1);
        cp16(Bhi + gb0 + k0, Bh + l0);
        cp16(Bhi + gb1 + k0, Bh + l1);
        cp16(Blo + gb0 + k0, Bl + l0);
        cp16(Blo + gb1 + k0, Bl + l1);
        __syncthreads();

        bf16x8 fa[4], fbh[4], fbl[4];
        #pragma unroll
        for (int i = 0; i < 4; i++){
            fa[i]  = *(const bf16x8*)&Ah[(wm + i*16 + fr)*BK + kc];
            fbh[i] = *(const bf16x8*)&Bh[(wn + i*16 + fr)*BK + kc];
            fbl[i] = *(const bf16x8*)&Bl[(wn + i*16 + fr)*BK + kc];
        }
        #pragma unroll
        for (int i = 0; i < 4; i++)
            #pragma unroll
            for (int j = 0; j < 4; j++){
                acc[i][j] = __builtin_amdgcn_mfma_f32_16x16x32_bf16(fa[i], fbh[j], acc[i][j], 0,0,0);
                acc[i][j] = __builtin_amdgcn_mfma_f32_16x16x32_bf16(fa[i], fbl[j], acc[i][j], 0,0,0);
            }
        __syncthreads();
    }

    const int mat = n0 / D_;   // block-uniform
    const float* bias = (mat==0) ? bq : (mat==1) ? bk : bv;
    const int col = lane & 15, rbase = (lane >> 4) * 4;
    #pragma unroll
    for (int j = 0; j < 4; j++){
        int nn = n0 + wn + j*16 + col - mat*D_;
        int h = nn >> 6, d = nn & 63;
        float bsv = bias[nn];
        #pragma unroll
        for (int i = 0; i < 4; i++){
            #pragma unroll
            for (int r = 0; r < 4; r++){
                int m = m0 + wm + i*16 + rbase + r;
                int bb = m >> 9, s = m & 511;
                size_t idx = (((size_t)bb*H_ + h)*S_ + s)*DH_ + d;
                float val = acc[i][j][r] + bsv;
                if (mat == 2) outv[idx] = val;
                else {
                    ushort_t hv = f2bf(val);
                    ushort_t lv = f2bf(val - bf2f(hv));
                    if (mat == 0){ qhi[idx] = hv; qlo[idx] = lv; }
                    else         { khi[idx] = hv; klo[idx] = lv; }
                }
            }
        }
    }
}

// ---------------------------------------------------------------------------
// MFMA sparsemax attention: low-LDS (20,480 B -> up to 7 blk/CU) two-half
// score exchange + sparse ballot-walk PV (r0 structure). NO launch-bounds
// min-waves directive: r3 (256,8)->VGPR32 and r4 (256,6)->VGPR40 both forced
// massive scratch spills (0.5-1.7 GB). Natural allocation ~60-80 VGPR; LDS is
// then the occupancy cap at 7 blocks/CU (~87%) vs r0's 4 (38%).
// Lane fr of quad owns keys {fr*16+[0,16)} U {256+fr*16+[0,16)} of its row.
// ---------------------------------------------------------------------------
#define SROW 320   // f32 per row: 16 owners x 20 (16 keys + 4 pad)

__global__ __launch_bounds__(256)
void attn_mfma(const ushort_t* __restrict__ Qhi, const ushort_t* __restrict__ Qlo,
               const ushort_t* __restrict__ Khi, const ushort_t* __restrict__ Klo,
               const float* __restrict__ V, const float* __restrict__ mask,
               float* __restrict__ out)
{
    __shared__ float sc[16*SROW];   // 20,480 B

    const int lane = threadIdx.x & 63;
    const int wave = threadIdx.x >> 6;         // 0..3
    const int fr = lane & 15, quad = lane >> 4;

    // XCD-bijective swizzle: 6144 blocks, 768 per XCD => 24 whole heads/XCD
    const int orig = blockIdx.x;
    const int swz  = (orig & 7) * (BH_*32/8) + (orig >> 3);
    const int bh = swz >> 5;
    const int q0 = (swz & 31) * 16;
    const int b = bh / H_, h = bh % H_;
    const size_t hb = (size_t)bh * S_ * DH_;

    // ---- Phase 1: QK^T scores (Q hi/lo x K hi/lo, 6 MFMAs per tile) -------
    bf16x8 qh[2], ql[2];
    {
        const ushort_t* qp  = Qhi + hb + (size_t)(q0 + fr)*DH_ + quad*8;
        const ushort_t* qp2 = Qlo + hb + (size_t)(q0 + fr)*DH_ + quad*8;
        qh[0] = *(const bf16x8*)qp;   qh[1] = *(const bf16x8*)(qp + 32);
        ql[0] = *(const bf16x8*)qp2;  ql[1] = *(const bf16x8*)(qp2 + 32);
    }

    f32x4 acc2[2][4];
    #pragma unroll
    for (int h2=0;h2<2;h2++)
        #pragma unroll
        for (int jj=0;jj<4;jj++) acc2[h2][jj] = (f32x4){0.f,0.f,0.f,0.f};

    __builtin_amdgcn_s_setprio(1);
    #pragma unroll
    for (int h2=0;h2<2;h2++){
        #pragma unroll
        for (int jj=0;jj<4;jj++){
            int kt = h2*256 + wave*64 + jj*16;
            const ushort_t* kp  = Khi + hb + (size_t)(kt + fr)*DH_ + quad*8;
            const ushort_t* kp2 = Klo + hb + (size_t)(kt + fr)*DH_ + quad*8;
            bf16x8 kh0 = *(const bf16x8*)kp;
            bf16x8 kh1 = *(const bf16x8*)(kp + 32);
            bf16x8 kl0 = *(const bf16x8*)kp2;
            bf16x8 kl1 = *(const bf16x8*)(kp2 + 32);
            f32x4 a = acc2[h2][jj];
            a = __builtin_amdgcn_mfma_f32_16x16x32_bf16(qh[0], kh0, a, 0,0,0);
            a = __builtin_amdgcn_mfma_f32_16x16x32_bf16(qh[1], kh1, a, 0,0,0);
            a = __builtin_amdgcn_mfma_f32_16x16x32_bf16(ql[0], kh0, a, 0,0,0);
            a = __builtin_amdgcn_mfma_f32_16x16x32_bf16(ql[1], kh1, a, 0,0,0);
            a = __builtin_amdgcn_mfma_f32_16x16x32_bf16(qh[0], kl0, a, 0,0,0);
            a = __builtin_amdgcn_mfma_f32_16x16x32_bf16(qh[1], kl1, a, 0,0,0);
            acc2[h2][jj] = a;
        }
    }
    __builtin_amdgcn_s_setprio(0);

    // ---- Half-exchange: scatter half0, read z[0..16), scatter half1, read
    const float* mrow = mask + b * S_;
    const int row = wave*4 + quad;
    float z[32];

    #pragma unroll
    for (int jj=0;jj<4;jj++){
        int k = wave*64 + jj*16 + fr;
        float mv = mrow[k];
        int o = wave*4 + jj;
        #pragma unroll
        for (int r=0;r<4;r++)
            sc[(quad*4+r)*SROW + o*20 + fr] = acc2[0][jj][r]*0.125f + mv;
    }
    __syncthreads();
    {
        const float* zp = &sc[row*SROW + fr*20];
        #pragma unroll
        for (int jj=0;jj<4;jj++){
            float4 t = *(const float4*)(zp + jj*4);
            z[jj*4+0]=t.x; z[jj*4+1]=t.y; z[jj*4+2]=t.z; z[jj*4+3]=t.w;
        }
    }
    __syncthreads();
    #pragma unroll
    for (int jj=0;jj<4;jj++){
        int k = 256 + wave*64 + jj*16 + fr;
        float mv = mrow[k];
        int o = wave*4 + jj;
        #pragma unroll
        for (int r=0;r<4;r++)
            sc[(quad*4+r)*SROW + o*20 + fr] = acc2[1][jj][r]*0.125f + mv;
    }
    __syncthreads();
    {
        const float* zp = &sc[row*SROW + fr*20];
        #pragma unroll
        for (int jj=0;jj<4;jj++){
            float4 t = *(const float4*)(zp + jj*4);
            z[16+jj*4+0]=t.x; z[16+jj*4+1]=t.y; z[16+jj*4+2]=t.z; z[16+jj*4+3]=t.w;
        }
    }
    // no further sc use -> no barrier needed

    // ---- Row max: depth-5 tree + 4-step intra-quad butterfly --------------
    float tau;
    {
        float red[16];
        #pragma unroll
        for (int i=0;i<16;i++) red[i] = fmaxf(z[i], z[i+16]);
        #pragma unroll
        for (int i=0;i<8;i++)  red[i] = fmaxf(red[i], red[i+8]);
        #pragma unroll
        for (int i=0;i<4;i++)  red[i] = fmaxf(red[i], red[i+4]);
        float mm = fmaxf(fmaxf(red[0],red[1]), fmaxf(red[2],red[3]));
        #pragma unroll
        for (int off=1; off<16; off<<=1) mm = fmaxf(mm, __shfl_xor(mm, off, 64));
        tau = mm - 1.0f;
    }

    // ---- Michelot fixed-point: 4-way partial sums, butterfly --------------
    for (int it=0; it<16; it++){
        float s0=0.f,s1=0.f,s2=0.f,s3=0.f;
        float k0=0.f,k1=0.f,k2=0.f,k3=0.f;
        #pragma unroll
        for (int i=0;i<32;i+=4){
            float z0=z[i], z1=z[i+1], z2=z[i+2], z3=z[i+3];
            if (z0 > tau){ s0 += z0; k0 += 1.f; }
            if (z1 > tau){ s1 += z1; k1 += 1.f; }
            if (z2 > tau){ s2 += z2; k2 += 1.f; }
            if (z3 > tau){ s3 += z3; k3 += 1.f; }
        }
        float ss = (s0+s1)+(s2+s3), kk = (k0+k1)+(k2+k3);
        #pragma unroll
        for (int off=1; off<16; off<<=1){
            ss += __shfl_xor(ss, off, 64);
            kk += __shfl_xor(kk, off, 64);
        }
        float tn = (ss - 1.0f) / kk;
        bool changed = (tn != tau);
        tau = tn;
        if (!__any(changed)) break;
    }

    // ---- Sparse PV: per-quad ballot walk; lane fr owns keys
    // {fr*16+i (i<16)} U {256+fr*16+(i-16) (i>=16)}. 4 quads walk 4 rows;
    // each support key: 16 lanes x float4 = 256B coalesced V-row read.
    float4 ctx = make_float4(0.f, 0.f, 0.f, 0.f);
    const float* vb = V + hb;
    #pragma unroll
    for (int i=0;i<32;i++){
        float p = z[i] - tau;
        unsigned long long bal = __ballot(p > 0.f);
        unsigned mk = (unsigned)((bal >> (quad*16)) & 0xFFFFull);
        const int base_i = (i < 16) ? i : (240 + i);   // s*16 + i  or 256 + s*16 + (i-16)
        while (mk){
            int s = __ffs(mk) - 1;
            mk &= mk - 1;
            float pv = __shfl(p, quad*16 + s, 64);
            const float4 vv = *(const float4*)(vb + (size_t)(base_i + s*16)*DH_ + fr*4);
            ctx.x += pv * vv.x;
            ctx.y += pv * vv.y;
            ctx.z += pv * vv.z;
            ctx.w += pv * vv.w;
        }
    }

    *(float4*)(out + (size_t)(b*S_ + q0 + row)*D_ + h*DH_ + fr*4) = ctx;
}

// ---------------------------------------------------------------------------
extern "C" void kernel_launch(void* const* d_in, const int* in_sizes, int n_in,
                              void* d_out, int out_size, void* d_ws, size_t ws_size,
                              hipStream_t stream) {
    const float* hs   = (const float*)d_in[0];
    const float* mask = (const float*)d_in[1];
    const float* Wq   = (const float*)d_in[2];
    const float* bq   = (const float*)d_in[3];
    const float* Wk   = (const float*)d_in[4];
    const float* bk   = (const float*)d_in[5];
    const float* Wv   = (const float*)d_in[6];
    const float* bv   = (const float*)d_in[7];
    float* out = (float*)d_out;

    const size_t per = (size_t)BH_ * S_ * DH_;   // 6291456
    char* w = (char*)d_ws;
    float*    vb  = (float*)w;    w += per*4;
    ushort_t* qhi = (ushort_t*)w; w += per*2;
    ushort_t* qlo = (ushort_t*)w; w += per*2;
    ushort_t* khi = (ushort_t*)w; w += per*2;
    ushort_t* klo = (ushort_t*)w; w += per*2;
    ushort_t* Xbf = (ushort_t*)w; w += per*2;
    ushort_t* Whi = (ushort_t*)w; w += (size_t)NTOT*D_*2;
    ushort_t* Wlo = (ushort_t*)w;

    convert_x<<<(int)(per/4/256), 256, 0, stream>>>(hs, Xbf, (int)(per/4));
    convert_w<<<dim3(D_*D_/4/256, 1, 3), 256, 0, stream>>>(Wq, Wk, Wv, Whi, Wlo);

    dim3 ggrid(NTOT/BN, MTOT/BM);   // (18, 64)
    gemm_split<<<ggrid, 256, 0, stream>>>(Xbf, Whi, Wlo, bq, bk, bv,
                                          qhi, qlo, khi, klo, vb);

    attn_mfma<<<BH_*32, 256, 0, stream>>>(qhi, qlo, khi, klo, vb, mask, out);
}

// Round 6
// 230.029 us; speedup vs baseline: 3.4383x; 1.3711x over previous
//
#include <hip/hip_runtime.h>
#include <math.h>

#define B_ 16
#define S_ 512
#define D_ 768
#define H_ 12
#define DH_ 64
#define BH_ (B_*H_)     // 192
#define MTOT (B_*S_)    // 8192
#define NTOT (3*D_)     // 2304

typedef unsigned short ushort_t;
typedef __attribute__((ext_vector_type(8))) _Float16 f16x8;
typedef __attribute__((ext_vector_type(4))) float f32x4;

__device__ __forceinline__ ushort_t f2h(float x){
    union { _Float16 h; ushort_t u; } c;
    c.h = (_Float16)x;              // v_cvt_f16_f32, RNE
    return c.u;
}

__device__ __forceinline__ void cp16(const void* g, void* l){
    __builtin_amdgcn_global_load_lds(
        (const __attribute__((address_space(1))) unsigned int*)g,
        (__attribute__((address_space(3))) unsigned int*)l, 16, 0, 0);
}

// ---------------------------------------------------------------------------
// f32 -> f16 (RNE), 4 elems/thread
// ---------------------------------------------------------------------------
__global__ __launch_bounds__(256)
void convert_x(const float* __restrict__ src, ushort_t* __restrict__ dst, int n4)
{
    int i = blockIdx.x * 256 + threadIdx.x;
    if (i >= n4) return;
    float4 x = ((const float4*)src)[i];
    union { ushort_t u[4]; uint2 v; } p;
    p.u[0] = f2h(x.x); p.u[1] = f2h(x.y);
    p.u[2] = f2h(x.z); p.u[3] = f2h(x.w);
    ((uint2*)dst)[i] = p.v;
}

// weights: all three matrices -> one f16 array
__global__ __launch_bounds__(256)
void convert_w(const float* __restrict__ Wq, const float* __restrict__ Wk,
               const float* __restrict__ Wv, ushort_t* __restrict__ dst)
{
    const float* src = (blockIdx.z==0) ? Wq : (blockIdx.z==1) ? Wk : Wv;
    const int n4 = D_*D_/4;
    int i = blockIdx.x * 256 + threadIdx.x;
    if (i >= n4) return;
    size_t off4 = (size_t)blockIdx.z * n4;
    float4 x = ((const float4*)src)[i];
    union { ushort_t u[4]; uint2 v; } p;
    p.u[0] = f2h(x.x); p.u[1] = f2h(x.y);
    p.u[2] = f2h(x.z); p.u[3] = f2h(x.w);
    ((uint2*)dst)[off4 + i] = p.v;
}

// ---------------------------------------------------------------------------
// MFMA GEMM (fp16 single-pass): C[m,n] = sum_k X[m,k]*W[n,k] + bias.
// fp16 (10-bit mantissa) replaces the bf16 hi/lo compensation scheme: half
// the MFMAs, 2 staged arrays instead of 3 (LDS 16 KB), half the epilogue
// stores. mat 0 -> Q f16, 1 -> K f16, 2 -> V f32 [bh][s][d] (walk PV).
// XCD-bijective block swizzle: 1152 blocks = 8 x 144; each XCD owns 8
// consecutive M-panels x all N (A panel 1.5 MB stays hot in its L2).
// ---------------------------------------------------------------------------
#define BM 128
#define BN 128
#define BK 32

__global__ __launch_bounds__(256)
void gemm_f16(const ushort_t* __restrict__ A, const ushort_t* __restrict__ Bw,
              const float* __restrict__ bq, const float* __restrict__ bk,
              const float* __restrict__ bv,
              ushort_t* __restrict__ qf, ushort_t* __restrict__ kf,
              float* __restrict__ outv)
{
    __shared__ ushort_t Ah[BM*BK], Bh[BN*BK];  // 16 KB

    const int tid  = threadIdx.x;
    const int lane = tid & 63, wave = tid >> 6;

    // XCD swizzle: flat id over (18 x 64) grid, x-fastest
    const int n = blockIdx.y * 18 + blockIdx.x;
    const int nn = (n & 7) * 144 + (n >> 3);
    const int bx = nn % 18, by = nn / 18;
    const int m0 = by * BM, n0 = bx * BN;
    const int wm = (wave >> 1) * 64, wn = (wave & 1) * 64;

    f32x4 acc[4][4];
    #pragma unroll
    for (int i=0;i<4;i++)
        #pragma unroll
        for (int j=0;j<4;j++) acc[i][j] = (f32x4){0.f,0.f,0.f,0.f};

    const int r0 = tid >> 2, c0 = (tid & 3) * 8;
    const size_t ga0 = (size_t)(m0 + r0)      * D_ + c0;
    const size_t ga1 = (size_t)(m0 + 64 + r0) * D_ + c0;
    const size_t gb0 = (size_t)(n0 + r0)      * D_ + c0;
    const size_t gb1 = (size_t)(n0 + 64 + r0) * D_ + c0;
    const int l0 = wave * 512;
    const int l1 = 2048 + wave * 512;

    const int fr = lane & 15, kc = (lane >> 4) * 8;

    for (int k0 = 0; k0 < D_; k0 += BK) {
        cp16(A  + ga0 + k0, Ah + l0);
        cp16(A  + ga1 + k0, Ah + l1);
        cp16(Bw + gb0 + k0, Bh + l0);
        cp16(Bw + gb1 + k0, Bh + l1);
        __syncthreads();

        f16x8 fa[4], fb[4];
        #pragma unroll
        for (int i = 0; i < 4; i++){
            fa[i] = *(const f16x8*)&Ah[(wm + i*16 + fr)*BK + kc];
            fb[i] = *(const f16x8*)&Bh[(wn + i*16 + fr)*BK + kc];
        }
        #pragma unroll
        for (int i = 0; i < 4; i++)
            #pragma unroll
            for (int j = 0; j < 4; j++)
                acc[i][j] = __builtin_amdgcn_mfma_f32_16x16x32_f16(fa[i], fb[j], acc[i][j], 0,0,0);
        __syncthreads();
    }

    const int mat = n0 / D_;   // block-uniform
    const float* bias = (mat==0) ? bq : (mat==1) ? bk : bv;
    const int col = lane & 15, rbase = (lane >> 4) * 4;
    #pragma unroll
    for (int j = 0; j < 4; j++){
        int nc = n0 + wn + j*16 + col - mat*D_;
        int h = nc >> 6, d = nc & 63;
        float bsv = bias[nc];
        #pragma unroll
        for (int i = 0; i < 4; i++){
            #pragma unroll
            for (int r = 0; r < 4; r++){
                int m = m0 + wm + i*16 + rbase + r;
                int bb = m >> 9, s = m & 511;
                size_t idx = (((size_t)bb*H_ + h)*S_ + s)*DH_ + d;
                float val = acc[i][j][r] + bsv;
                if (mat == 2) outv[idx] = val;
                else if (mat == 0) qf[idx] = f2h(val);
                else               kf[idx] = f2h(val);
            }
        }
    }
}

// ---------------------------------------------------------------------------
// MFMA sparsemax attention (fp16 QK^T): low-LDS (20,480 B) two-half score
// exchange + sparse ballot-walk PV. Q,K single fp16 -> 2 MFMAs per 16-key
// tile (was 6 with bf16 hi/lo). No launch-bounds min-waves (r3/r4: any such
// directive forced 0.5-1.7 GB scratch spills). Lane fr of quad owns keys
// {fr*16+[0,16)} U {256+fr*16+[0,16)} of its row.
// ---------------------------------------------------------------------------
#define SROW 320   // f32 per row: 16 owners x 20 (16 keys + 4 pad)

__global__ __launch_bounds__(256)
void attn_mfma(const ushort_t* __restrict__ Qf, const ushort_t* __restrict__ Kf,
               const float* __restrict__ V, const float* __restrict__ mask,
               float* __restrict__ out)
{
    __shared__ float sc[16*SROW];   // 20,480 B

    const int lane = threadIdx.x & 63;
    const int wave = threadIdx.x >> 6;         // 0..3
    const int fr = lane & 15, quad = lane >> 4;

    // XCD-bijective swizzle: 6144 blocks, 768 per XCD => 24 whole heads/XCD
    const int orig = blockIdx.x;
    const int swz  = (orig & 7) * (BH_*32/8) + (orig >> 3);
    const int bh = swz >> 5;
    const int q0 = (swz & 31) * 16;
    const int b = bh / H_, h = bh % H_;
    const size_t hb = (size_t)bh * S_ * DH_;

    // ---- Phase 1: QK^T scores (fp16, 2 MFMAs per 16-key tile) -------------
    f16x8 qh[2];
    {
        const ushort_t* qp = Qf + hb + (size_t)(q0 + fr)*DH_ + quad*8;
        qh[0] = *(const f16x8*)qp;
        qh[1] = *(const f16x8*)(qp + 32);
    }

    f32x4 acc2[2][4];
    #pragma unroll
    for (int h2=0;h2<2;h2++)
        #pragma unroll
        for (int jj=0;jj<4;jj++) acc2[h2][jj] = (f32x4){0.f,0.f,0.f,0.f};

    __builtin_amdgcn_s_setprio(1);
    #pragma unroll
    for (int h2=0;h2<2;h2++){
        #pragma unroll
        for (int jj=0;jj<4;jj++){
            int kt = h2*256 + wave*64 + jj*16;
            const ushort_t* kp = Kf + hb + (size_t)(kt + fr)*DH_ + quad*8;
            f16x8 k0 = *(const f16x8*)kp;
            f16x8 k1 = *(const f16x8*)(kp + 32);
            f32x4 a = acc2[h2][jj];
            a = __builtin_amdgcn_mfma_f32_16x16x32_f16(qh[0], k0, a, 0,0,0);
            a = __builtin_amdgcn_mfma_f32_16x16x32_f16(qh[1], k1, a, 0,0,0);
            acc2[h2][jj] = a;
        }
    }
    __builtin_amdgcn_s_setprio(0);

    // ---- Half-exchange: scatter half0, read z[0..16), scatter half1, read
    const float* mrow = mask + b * S_;
    const int row = wave*4 + quad;
    float z[32];

    #pragma unroll
    for (int jj=0;jj<4;jj++){
        int k = wave*64 + jj*16 + fr;
        float mv = mrow[k];
        int o = wave*4 + jj;
        #pragma unroll
        for (int r=0;r<4;r++)
            sc[(quad*4+r)*SROW + o*20 + fr] = acc2[0][jj][r]*0.125f + mv;
    }
    __syncthreads();
    {
        const float* zp = &sc[row*SROW + fr*20];
        #pragma unroll
        for (int jj=0;jj<4;jj++){
            float4 t = *(const float4*)(zp + jj*4);
            z[jj*4+0]=t.x; z[jj*4+1]=t.y; z[jj*4+2]=t.z; z[jj*4+3]=t.w;
        }
    }
    __syncthreads();
    #pragma unroll
    for (int jj=0;jj<4;jj++){
        int k = 256 + wave*64 + jj*16 + fr;
        float mv = mrow[k];
        int o = wave*4 + jj;
        #pragma unroll
        for (int r=0;r<4;r++)
            sc[(quad*4+r)*SROW + o*20 + fr] = acc2[1][jj][r]*0.125f + mv;
    }
    __syncthreads();
    {
        const float* zp = &sc[row*SROW + fr*20];
        #pragma unroll
        for (int jj=0;jj<4;jj++){
            float4 t = *(const float4*)(zp + jj*4);
            z[16+jj*4+0]=t.x; z[16+jj*4+1]=t.y; z[16+jj*4+2]=t.z; z[16+jj*4+3]=t.w;
        }
    }
    // no further sc use -> no barrier needed

    // ---- Row max: depth-5 tree + 4-step intra-quad butterfly --------------
    float tau;
    {
        float red[16];
        #pragma unroll
        for (int i=0;i<16;i++) red[i] = fmaxf(z[i], z[i+16]);
        #pragma unroll
        for (int i=0;i<8;i++)  red[i] = fmaxf(red[i], red[i+8]);
        #pragma unroll
        for (int i=0;i<4;i++)  red[i] = fmaxf(red[i], red[i+4]);
        float mm = fmaxf(fmaxf(red[0],red[1]), fmaxf(red[2],red[3]));
        #pragma unroll
        for (int off=1; off<16; off<<=1) mm = fmaxf(mm, __shfl_xor(mm, off, 64));
        tau = mm - 1.0f;
    }

    // ---- Michelot fixed-point: 4-way partial sums, butterfly --------------
    for (int it=0; it<16; it++){
        float s0=0.f,s1=0.f,s2=0.f,s3=0.f;
        float k0=0.f,k1=0.f,k2=0.f,k3=0.f;
        #pragma unroll
        for (int i=0;i<32;i+=4){
            float z0=z[i], z1=z[i+1], z2=z[i+2], z3=z[i+3];
            if (z0 > tau){ s0 += z0; k0 += 1.f; }
            if (z1 > tau){ s1 += z1; k1 += 1.f; }
            if (z2 > tau){ s2 += z2; k2 += 1.f; }
            if (z3 > tau){ s3 += z3; k3 += 1.f; }
        }
        float ss = (s0+s1)+(s2+s3), kk = (k0+k1)+(k2+k3);
        #pragma unroll
        for (int off=1; off<16; off<<=1){
            ss += __shfl_xor(ss, off, 64);
            kk += __shfl_xor(kk, off, 64);
        }
        float tn = (ss - 1.0f) / kk;
        bool changed = (tn != tau);
        tau = tn;
        if (!__any(changed)) break;
    }

    // ---- Sparse PV: per-quad ballot walk; each support key: 16 lanes x
    // float4 = 256B coalesced V-row read.
    float4 ctx = make_float4(0.f, 0.f, 0.f, 0.f);
    const float* vb = V + hb;
    #pragma unroll
    for (int i=0;i<32;i++){
        float p = z[i] - tau;
        unsigned long long bal = __ballot(p > 0.f);
        unsigned mk = (unsigned)((bal >> (quad*16)) & 0xFFFFull);
        const int base_i = (i < 16) ? i : (240 + i);   // s*16+i  or 256+s*16+(i-16)
        while (mk){
            int s = __ffs(mk) - 1;
            mk &= mk - 1;
            float pv = __shfl(p, quad*16 + s, 64);
            const float4 vv = *(const float4*)(vb + (size_t)(base_i + s*16)*DH_ + fr*4);
            ctx.x += pv * vv.x;
            ctx.y += pv * vv.y;
            ctx.z += pv * vv.z;
            ctx.w += pv * vv.w;
        }
    }

    *(float4*)(out + (size_t)(b*S_ + q0 + row)*D_ + h*DH_ + fr*4) = ctx;
}

// ---------------------------------------------------------------------------
extern "C" void kernel_launch(void* const* d_in, const int* in_sizes, int n_in,
                              void* d_out, int out_size, void* d_ws, size_t ws_size,
                              hipStream_t stream) {
    const float* hs   = (const float*)d_in[0];
    const float* mask = (const float*)d_in[1];
    const float* Wq   = (const float*)d_in[2];
    const float* bq   = (const float*)d_in[3];
    const float* Wk   = (const float*)d_in[4];
    const float* bk   = (const float*)d_in[5];
    const float* Wv   = (const float*)d_in[6];
    const float* bv   = (const float*)d_in[7];
    float* out = (float*)d_out;

    const size_t per = (size_t)BH_ * S_ * DH_;   // 6291456
    char* w = (char*)d_ws;
    float*    vb  = (float*)w;    w += per*4;
    ushort_t* qf  = (ushort_t*)w; w += per*2;
    ushort_t* kf  = (ushort_t*)w; w += per*2;
    ushort_t* Xf  = (ushort_t*)w; w += per*2;
    ushort_t* Wf  = (ushort_t*)w;

    convert_x<<<(int)(per/4/256), 256, 0, stream>>>(hs, Xf, (int)(per/4));
    convert_w<<<dim3(D_*D_/4/256, 1, 3), 256, 0, stream>>>(Wq, Wk, Wv, Wf);

    dim3 ggrid(NTOT/BN, MTOT/BM);   // (18, 64)
    gemm_f16<<<ggrid, 256, 0, stream>>>(Xf, Wf, bq, bk, bv, qf, kf, vb);

    attn_mfma<<<BH_*32, 256, 0, stream>>>(qf, kf, vb, mask, out);
}